// Round 1
// baseline (10661.008 us; speedup 1.0000x reference)
//
#include <hip/hip_runtime.h>
#include <hip/hip_bf16.h>

// ---------------- constants ----------------
#define NUM_USERS 50000
#define NUM_ITEMS 20000
#define NUM_NODES (NUM_USERS + NUM_ITEMS)
#define FEAT_DIM 768
#define HID 128
#define H1DIM 512
#define LN_EPS 1e-5f
#define ALPHA 0.25f

// ---------------- tiled fp32 GEMM: C = A(MxK) @ B(KxN) + bias ----------------
// BM=BN=64, BK=16, 256 threads, 4x4 micro-tile per thread.
__global__ __launch_bounds__(256) void gemm_bias(
    const float* __restrict__ A, const float* __restrict__ B,
    const float* __restrict__ bias, float* __restrict__ C,
    int M, int N, int K) {
  const int BM = 64, BN = 64, BK = 16;
  __shared__ float As[BK][BM + 4];  // transposed A tile, +4 pad keeps 16B align
  __shared__ float Bs[BK][BN];

  int tid = threadIdx.x;
  int bm = blockIdx.y * BM, bn = blockIdx.x * BN;
  int tx = tid & 15;   // 0..15 -> N
  int ty = tid >> 4;   // 0..15 -> M

  float acc[4][4] = {};

  int arow = tid >> 2;          // 0..63
  int acol = (tid & 3) * 4;     // 0,4,8,12
  int brow = tid >> 4;          // 0..15
  int bcol = (tid & 15) * 4;    // 0..60

  for (int k0 = 0; k0 < K; k0 += BK) {
    float4 av = make_float4(0.f, 0.f, 0.f, 0.f);
    if (bm + arow < M)
      av = *(const float4*)&A[(size_t)(bm + arow) * K + k0 + acol];
    As[acol + 0][arow] = av.x;
    As[acol + 1][arow] = av.y;
    As[acol + 2][arow] = av.z;
    As[acol + 3][arow] = av.w;
    *(float4*)&Bs[brow][bcol] =
        *(const float4*)&B[(size_t)(k0 + brow) * N + bn + bcol];
    __syncthreads();
#pragma unroll
    for (int kk = 0; kk < BK; kk++) {
      float a[4], b[4];
#pragma unroll
      for (int i = 0; i < 4; i++) a[i] = As[kk][ty * 4 + i];
#pragma unroll
      for (int j = 0; j < 4; j++) b[j] = Bs[kk][tx * 4 + j];
#pragma unroll
      for (int i = 0; i < 4; i++)
#pragma unroll
        for (int j = 0; j < 4; j++) acc[i][j] = fmaf(a[i], b[j], acc[i][j]);
    }
    __syncthreads();
  }

#pragma unroll
  for (int i = 0; i < 4; i++) {
    int r = bm + ty * 4 + i;
    if (r >= M) continue;
#pragma unroll
    for (int j = 0; j < 4; j++) {
      int c = bn + tx * 4 + j;
      C[(size_t)r * N + c] = acc[i][j] + bias[c];
    }
  }
}

// ---------------- LayerNorm+ReLU, width 512, one block(256) per row ----------
__global__ __launch_bounds__(256) void ln_relu_w512(
    float* __restrict__ X, const float* __restrict__ g,
    const float* __restrict__ be) {
  int row = blockIdx.x, t = threadIdx.x;
  float* x = X + (size_t)row * H1DIM;
  float v0 = x[t], v1 = x[t + 256];
  float s = v0 + v1, q = v0 * v0 + v1 * v1;
#pragma unroll
  for (int off = 32; off > 0; off >>= 1) {
    s += __shfl_down(s, off);
    q += __shfl_down(q, off);
  }
  __shared__ float ss[4], qq[4];
  int lane = t & 63, wid = t >> 6;
  if (lane == 0) { ss[wid] = s; qq[wid] = q; }
  __syncthreads();
  float S = ss[0] + ss[1] + ss[2] + ss[3];
  float Q = qq[0] + qq[1] + qq[2] + qq[3];
  float mu = S * (1.f / 512.f);
  float var = Q * (1.f / 512.f) - mu * mu;
  float rs = rsqrtf(var + LN_EPS);
  float y0 = (v0 - mu) * rs * g[t] + be[t];
  float y1 = (v1 - mu) * rs * g[t + 256] + be[t + 256];
  x[t] = fmaxf(y0, 0.f);
  x[t + 256] = fmaxf(y1, 0.f);
}

// ---------------- LayerNorm+ReLU, width 128, one wave per row ----------------
__global__ __launch_bounds__(256) void ln_relu_w128(
    float* __restrict__ X, const float* __restrict__ g,
    const float* __restrict__ be, int rows) {
  int gwid = (blockIdx.x * blockDim.x + threadIdx.x) >> 6;
  if (gwid >= rows) return;
  int lane = threadIdx.x & 63;
  float* x = X + (size_t)gwid * HID;
  float v0 = x[lane], v1 = x[lane + 64];
  float s = v0 + v1, q = v0 * v0 + v1 * v1;
#pragma unroll
  for (int off = 32; off > 0; off >>= 1) {
    s += __shfl_down(s, off);
    q += __shfl_down(q, off);
  }
  s = __shfl(s, 0);
  q = __shfl(q, 0);
  float mu = s * (1.f / 128.f);
  float var = q * (1.f / 128.f) - mu * mu;
  float rs = rsqrtf(var + LN_EPS);
  float y0 = (v0 - mu) * rs * g[lane] + be[lane];
  float y1 = (v1 - mu) * rs * g[lane + 64] + be[lane + 64];
  x[lane] = fmaxf(y0, 0.f);
  x[lane + 64] = fmaxf(y1, 0.f);
}

// -------- GEMM3 (128x128) fused with L2-normalize, one block(128) per row ----
__global__ __launch_bounds__(128) void gemm3_norm(
    const float* __restrict__ H, const float* __restrict__ W3,
    const float* __restrict__ b3, float* __restrict__ meta) {
  int r = blockIdx.x, t = threadIdx.x;
  __shared__ float hrow[HID];
  hrow[t] = H[(size_t)r * HID + t];
  __syncthreads();
  float s = b3[t];
#pragma unroll 8
  for (int k = 0; k < HID; k++) s = fmaf(hrow[k], W3[k * HID + t], s);
  float q = s * s;
#pragma unroll
  for (int off = 32; off > 0; off >>= 1) q += __shfl_down(q, off);
  __shared__ float qs[2];
  if ((t & 63) == 0) qs[t >> 6] = q;
  __syncthreads();
  float nrm = fmaxf(sqrtf(qs[0] + qs[1]), 1e-12f);
  meta[(size_t)r * HID + t] = s / nrm;
}

// --------- build e0 = [emb_users; emb_items + mw*meta], out = alpha*e0 -------
__global__ __launch_bounds__(256) void build_e0(
    const float* __restrict__ emb, const float* __restrict__ meta,
    const float* __restrict__ mw_p, float* __restrict__ x0,
    float* __restrict__ out) {
  size_t i = (size_t)blockIdx.x * 256 + threadIdx.x;  // < 70000*128, exact grid
  float e = emb[i];
  size_t node = i >> 7;
  if (node >= NUM_USERS) e += mw_p[0] * meta[i - (size_t)NUM_USERS * HID];
  x0[i] = e;
  out[i] = ALPHA * e;
}

// ---------------- degree count / dinv / edge weights -------------------------
__global__ __launch_bounds__(256) void count_deg(const int* __restrict__ dst,
                                                 int* __restrict__ deg, int E) {
  int e = blockIdx.x * 256 + threadIdx.x;
  if (e < E) atomicAdd(&deg[dst[e]], 1);
}

__global__ __launch_bounds__(256) void calc_dinv(const int* __restrict__ deg,
                                                 float* __restrict__ dinv, int n) {
  int i = blockIdx.x * 256 + threadIdx.x;
  if (i < n) dinv[i] = deg[i] > 0 ? rsqrtf((float)deg[i]) : 0.f;
}

__global__ __launch_bounds__(256) void edge_w(const int* __restrict__ src,
                                              const int* __restrict__ dst,
                                              const float* __restrict__ dinv,
                                              float* __restrict__ w, int E) {
  int e = blockIdx.x * 256 + threadIdx.x;
  if (e < E) w[e] = dinv[src[e]] * dinv[dst[e]];
}

// ---------------- SpMM scatter: y[dst] += w * x[src] -------------------------
// 32 lanes per edge, float4 per lane (128 feats).
__global__ __launch_bounds__(256) void spmm_scatter(
    const int* __restrict__ src, const int* __restrict__ dst,
    const float* __restrict__ w, const float* __restrict__ x,
    float* __restrict__ y, int E) {
  int t = blockIdx.x * 256 + threadIdx.x;
  int e = t >> 5;
  if (e >= E) return;
  int q = (t & 31) * 4;
  int s = src[e], d = dst[e];
  float ww = w[e];
  float4 v = *(const float4*)&x[(size_t)s * HID + q];
  float* yp = &y[(size_t)d * HID + q];
  atomicAdd(yp + 0, ww * v.x);
  atomicAdd(yp + 1, ww * v.y);
  atomicAdd(yp + 2, ww * v.z);
  atomicAdd(yp + 3, ww * v.w);
}

// ---------------- out += alpha * x -------------------------------------------
__global__ __launch_bounds__(256) void axpy_alpha(float* __restrict__ out,
                                                  const float* __restrict__ x) {
  size_t i = (size_t)blockIdx.x * 256 + threadIdx.x;  // exact grid
  out[i] += ALPHA * x[i];
}

// ---------------- launcher ---------------------------------------------------
extern "C" void kernel_launch(void* const* d_in, const int* in_sizes, int n_in,
                              void* d_out, int out_size, void* d_ws,
                              size_t ws_size, hipStream_t stream) {
  const int* edge = (const int*)d_in[0];
  const float* item_feat = (const float*)d_in[1];
  const float* emb = (const float*)d_in[2];
  const float* W1 = (const float*)d_in[3];
  const float* b1 = (const float*)d_in[4];
  const float* g1 = (const float*)d_in[5];
  const float* be1 = (const float*)d_in[6];
  const float* W2 = (const float*)d_in[7];
  const float* b2 = (const float*)d_in[8];
  const float* g2 = (const float*)d_in[9];
  const float* be2 = (const float*)d_in[10];
  const float* W3 = (const float*)d_in[11];
  const float* b3 = (const float*)d_in[12];
  const float* mw = (const float*)d_in[13];
  float* out = (float*)d_out;

  const int E = in_sizes[0] / 2;
  const int* src = edge;
  const int* dst = edge + E;

  // workspace layout (all offsets multiple of 256B)
  char* ws = (char*)d_ws;
  float* h1 = (float*)(ws + 0);                      // 20000*512*4 = 40,960,000
  float* h2 = (float*)(ws + 40960000);               // 20000*128*4 = 10,240,000
  float* xA = (float*)(ws + 51200000);               // 70000*128*4 = 35,840,000
  float* xB = (float*)(ws + 87040000);               // 35,840,000
  int*   deg = (int*)(ws + 122880000);               // 70000*4
  float* dinv = (float*)(ws + 123160064);            // 70000*4
  float* w = (float*)(ws + 123440384);               // 2,000,000*4
  float* meta = h1;  // alias: h1 is dead by the time meta is written

  // ---- item metadata MLP ----
  {
    dim3 g(H1DIM / 64, (NUM_ITEMS + 63) / 64);
    gemm_bias<<<g, 256, 0, stream>>>(item_feat, W1, b1, h1, NUM_ITEMS, H1DIM,
                                     FEAT_DIM);
  }
  ln_relu_w512<<<NUM_ITEMS, 256, 0, stream>>>(h1, g1, be1);
  {
    dim3 g(HID / 64, (NUM_ITEMS + 63) / 64);
    gemm_bias<<<g, 256, 0, stream>>>(h1, W2, b2, h2, NUM_ITEMS, HID, H1DIM);
  }
  ln_relu_w128<<<(NUM_ITEMS * 64 + 255) / 256, 256, 0, stream>>>(h2, g2, be2,
                                                                 NUM_ITEMS);
  gemm3_norm<<<NUM_ITEMS, 128, 0, stream>>>(h2, W3, b3, meta);

  // ---- e0 and out init ----
  build_e0<<<(NUM_NODES * HID) / 256, 256, 0, stream>>>(emb, meta, mw, xA, out);

  // ---- graph normalization ----
  hipMemsetAsync(deg, 0, NUM_NODES * sizeof(int), stream);
  count_deg<<<(E + 255) / 256, 256, 0, stream>>>(dst, deg, E);
  calc_dinv<<<(NUM_NODES + 255) / 256, 256, 0, stream>>>(deg, dinv, NUM_NODES);
  edge_w<<<(E + 255) / 256, 256, 0, stream>>>(src, dst, dinv, w, E);

  // ---- 3 propagation layers ----
  float* xcur = xA;
  float* xnext = xB;
  for (int l = 0; l < 3; l++) {
    hipMemsetAsync(xnext, 0, (size_t)NUM_NODES * HID * sizeof(float), stream);
    spmm_scatter<<<(size_t)E * 32 / 256, 256, 0, stream>>>(src, dst, w, xcur,
                                                           xnext, E);
    axpy_alpha<<<(NUM_NODES * HID) / 256, 256, 0, stream>>>(out, xnext);
    float* tmp = xcur; xcur = xnext; xnext = tmp;
  }
}

// Round 3
// 1194.930 us; speedup vs baseline: 8.9219x; 8.9219x over previous
//
#include <hip/hip_runtime.h>
#include <hip/hip_bf16.h>

// ---------------- constants ----------------
#define NUM_USERS 50000
#define NUM_ITEMS 20000
#define NUM_NODES (NUM_USERS + NUM_ITEMS)
#define FEAT_DIM 768
#define HID 128
#define H1DIM 512
#define LN_EPS 1e-5f
#define ALPHA 0.25f

// ---------------- tiled fp32 GEMM: C = A(MxK) @ B(KxN) + bias ----------------
__global__ __launch_bounds__(256) void gemm_bias(
    const float* __restrict__ A, const float* __restrict__ B,
    const float* __restrict__ bias, float* __restrict__ C,
    int M, int N, int K) {
  const int BM = 64, BN = 64, BK = 16;
  __shared__ float As[BK][BM + 4];
  __shared__ float Bs[BK][BN];

  int tid = threadIdx.x;
  int bm = blockIdx.y * BM, bn = blockIdx.x * BN;
  int tx = tid & 15;
  int ty = tid >> 4;

  float acc[4][4] = {};

  int arow = tid >> 2;
  int acol = (tid & 3) * 4;
  int brow = tid >> 4;
  int bcol = (tid & 15) * 4;

  for (int k0 = 0; k0 < K; k0 += BK) {
    float4 av = make_float4(0.f, 0.f, 0.f, 0.f);
    if (bm + arow < M)
      av = *(const float4*)&A[(size_t)(bm + arow) * K + k0 + acol];
    As[acol + 0][arow] = av.x;
    As[acol + 1][arow] = av.y;
    As[acol + 2][arow] = av.z;
    As[acol + 3][arow] = av.w;
    *(float4*)&Bs[brow][bcol] =
        *(const float4*)&B[(size_t)(k0 + brow) * N + bn + bcol];
    __syncthreads();
#pragma unroll
    for (int kk = 0; kk < BK; kk++) {
      float a[4], b[4];
#pragma unroll
      for (int i = 0; i < 4; i++) a[i] = As[kk][ty * 4 + i];
#pragma unroll
      for (int j = 0; j < 4; j++) b[j] = Bs[kk][tx * 4 + j];
#pragma unroll
      for (int i = 0; i < 4; i++)
#pragma unroll
        for (int j = 0; j < 4; j++) acc[i][j] = fmaf(a[i], b[j], acc[i][j]);
    }
    __syncthreads();
  }

#pragma unroll
  for (int i = 0; i < 4; i++) {
    int r = bm + ty * 4 + i;
    if (r >= M) continue;
#pragma unroll
    for (int j = 0; j < 4; j++) {
      int c = bn + tx * 4 + j;
      C[(size_t)r * N + c] = acc[i][j] + bias[c];
    }
  }
}

// ---------------- LayerNorm+ReLU, width 512, one block(256) per row ----------
__global__ __launch_bounds__(256) void ln_relu_w512(
    float* __restrict__ X, const float* __restrict__ g,
    const float* __restrict__ be) {
  int row = blockIdx.x, t = threadIdx.x;
  float* x = X + (size_t)row * H1DIM;
  float v0 = x[t], v1 = x[t + 256];
  float s = v0 + v1, q = v0 * v0 + v1 * v1;
#pragma unroll
  for (int off = 32; off > 0; off >>= 1) {
    s += __shfl_down(s, off);
    q += __shfl_down(q, off);
  }
  __shared__ float ss[4], qq[4];
  int lane = t & 63, wid = t >> 6;
  if (lane == 0) { ss[wid] = s; qq[wid] = q; }
  __syncthreads();
  float S = ss[0] + ss[1] + ss[2] + ss[3];
  float Q = qq[0] + qq[1] + qq[2] + qq[3];
  float mu = S * (1.f / 512.f);
  float var = Q * (1.f / 512.f) - mu * mu;
  float rs = rsqrtf(var + LN_EPS);
  float y0 = (v0 - mu) * rs * g[t] + be[t];
  float y1 = (v1 - mu) * rs * g[t + 256] + be[t + 256];
  x[t] = fmaxf(y0, 0.f);
  x[t + 256] = fmaxf(y1, 0.f);
}

// ---------------- LayerNorm+ReLU, width 128, one wave per row ----------------
__global__ __launch_bounds__(256) void ln_relu_w128(
    float* __restrict__ X, const float* __restrict__ g,
    const float* __restrict__ be, int rows) {
  int gwid = (blockIdx.x * blockDim.x + threadIdx.x) >> 6;
  if (gwid >= rows) return;
  int lane = threadIdx.x & 63;
  float* x = X + (size_t)gwid * HID;
  float v0 = x[lane], v1 = x[lane + 64];
  float s = v0 + v1, q = v0 * v0 + v1 * v1;
#pragma unroll
  for (int off = 32; off > 0; off >>= 1) {
    s += __shfl_down(s, off);
    q += __shfl_down(q, off);
  }
  s = __shfl(s, 0);
  q = __shfl(q, 0);
  float mu = s * (1.f / 128.f);
  float var = q * (1.f / 128.f) - mu * mu;
  float rs = rsqrtf(var + LN_EPS);
  float y0 = (v0 - mu) * rs * g[lane] + be[lane];
  float y1 = (v1 - mu) * rs * g[lane + 64] + be[lane + 64];
  x[lane] = fmaxf(y0, 0.f);
  x[lane + 64] = fmaxf(y1, 0.f);
}

// -------- GEMM3 (128x128) fused with L2-normalize, one block(128) per row ----
__global__ __launch_bounds__(128) void gemm3_norm(
    const float* __restrict__ H, const float* __restrict__ W3,
    const float* __restrict__ b3, float* __restrict__ meta) {
  int r = blockIdx.x, t = threadIdx.x;
  __shared__ float hrow[HID];
  hrow[t] = H[(size_t)r * HID + t];
  __syncthreads();
  float s = b3[t];
#pragma unroll 8
  for (int k = 0; k < HID; k++) s = fmaf(hrow[k], W3[k * HID + t], s);
  float q = s * s;
#pragma unroll
  for (int off = 32; off > 0; off >>= 1) q += __shfl_down(q, off);
  __shared__ float qs[2];
  if ((t & 63) == 0) qs[t >> 6] = q;
  __syncthreads();
  float nrm = fmaxf(sqrtf(qs[0] + qs[1]), 1e-12f);
  meta[(size_t)r * HID + t] = s / nrm;
}

// --------- build e0 = [emb_users; emb_items + mw*meta], out = alpha*e0 -------
__global__ __launch_bounds__(256) void build_e0(
    const float* __restrict__ emb, const float* __restrict__ meta,
    const float* __restrict__ mw_p, float* __restrict__ x0,
    float* __restrict__ out) {
  size_t i = (size_t)blockIdx.x * 256 + threadIdx.x;  // exact grid
  float e = emb[i];
  size_t node = i >> 7;
  if (node >= NUM_USERS) e += mw_p[0] * meta[i - (size_t)NUM_USERS * HID];
  x0[i] = e;
  out[i] = ALPHA * e;
}

// ---------------- degree count / dinv ----------------------------------------
__global__ __launch_bounds__(256) void count_deg(const int* __restrict__ dst,
                                                 int* __restrict__ deg, int E) {
  int e = blockIdx.x * 256 + threadIdx.x;
  if (e < E) atomicAdd(&deg[dst[e]], 1);
}

__global__ __launch_bounds__(256) void calc_dinv(const int* __restrict__ deg,
                                                 float* __restrict__ dinv, int n) {
  int i = blockIdx.x * 256 + threadIdx.x;
  if (i < n) dinv[i] = deg[i] > 0 ? rsqrtf((float)deg[i]) : 0.f;
}

// ---------------- exclusive scan (3-kernel, n=70000) -------------------------
__global__ __launch_bounds__(256) void scan1(const int* __restrict__ deg,
                                             int* __restrict__ rowptr,
                                             int* __restrict__ bsum, int n) {
  int i = blockIdx.x * 256 + threadIdx.x;
  int v = (i < n) ? deg[i] : 0;
  int lane = threadIdx.x & 63, wid = threadIdx.x >> 6;
  int s = v;
#pragma unroll
  for (int off = 1; off < 64; off <<= 1) {
    int t = __shfl_up(s, off);
    if (lane >= off) s += t;
  }
  __shared__ int wsum[4];
  if (lane == 63) wsum[wid] = s;
  __syncthreads();
  int add = 0;
  for (int w = 0; w < wid; w++) add += wsum[w];
  int incl = s + add;
  if (i < n) rowptr[i] = incl - v;  // exclusive
  if (threadIdx.x == 255) bsum[blockIdx.x] = incl;  // block total
}

__global__ void scan2(int* __restrict__ bsum, int nb) {
  // single thread serial exclusive scan over ~274 block sums
  if (threadIdx.x == 0 && blockIdx.x == 0) {
    int run = 0;
    for (int i = 0; i < nb; i++) {
      int v = bsum[i];
      bsum[i] = run;
      run += v;
    }
  }
}

__global__ __launch_bounds__(256) void scan3(int* __restrict__ rowptr,
                                             const int* __restrict__ bsum,
                                             int n, int E) {
  int i = blockIdx.x * 256 + threadIdx.x;
  if (i < n) rowptr[i] += bsum[blockIdx.x];
  if (i == 0) rowptr[n] = E;
}

// ---------------- CSR fill ---------------------------------------------------
__global__ __launch_bounds__(256) void fill_csr(const int* __restrict__ src,
                                                const int* __restrict__ dst,
                                                int* __restrict__ cursor,
                                                int* __restrict__ csr_src,
                                                int E) {
  int e = blockIdx.x * 256 + threadIdx.x;
  if (e < E) {
    int pos = atomicAdd(&cursor[dst[e]], 1);
    csr_src[pos] = src[e];
  }
}

// ---------------- SpMM gather: one wave per dst row --------------------------
// y[row] = sum_{s in N(row)} dinv[row]*dinv[s] * x[s];  out[row] += alpha*y[row]
__global__ __launch_bounds__(256) void spmm_gather(
    const int* __restrict__ rowptr, const int* __restrict__ csr_src,
    const float* __restrict__ dinv, const float* __restrict__ x,
    float* __restrict__ y, float* __restrict__ out) {
  int row = (blockIdx.x * 256 + threadIdx.x) >> 6;  // 4 waves/block, exact grid
  int lane = threadIdx.x & 63;
  int beg = rowptr[row], end = rowptr[row + 1];
  float wd = dinv[row];
  float ax = 0.f, ay = 0.f;
  int p = beg;
  // unroll-by-2 for a little MLP (memory-level parallelism)
  for (; p + 2 <= end; p += 2) {
    int s0 = csr_src[p], s1 = csr_src[p + 1];
    float c0 = wd * dinv[s0], c1 = wd * dinv[s1];
    float2 v0 = *(const float2*)&x[(size_t)s0 * HID + lane * 2];
    float2 v1 = *(const float2*)&x[(size_t)s1 * HID + lane * 2];
    ax += c0 * v0.x + c1 * v1.x;
    ay += c0 * v0.y + c1 * v1.y;
  }
  if (p < end) {
    int s0 = csr_src[p];
    float c0 = wd * dinv[s0];
    float2 v0 = *(const float2*)&x[(size_t)s0 * HID + lane * 2];
    ax += c0 * v0.x;
    ay += c0 * v0.y;
  }
  size_t o = (size_t)row * HID + lane * 2;
  float2 res = make_float2(ax, ay);
  *(float2*)&y[o] = res;
  float2 po = *(const float2*)&out[o];
  po.x += ALPHA * ax;
  po.y += ALPHA * ay;
  *(float2*)&out[o] = po;
}

// ---------------- launcher ---------------------------------------------------
extern "C" void kernel_launch(void* const* d_in, const int* in_sizes, int n_in,
                              void* d_out, int out_size, void* d_ws,
                              size_t ws_size, hipStream_t stream) {
  const int* edge = (const int*)d_in[0];
  const float* item_feat = (const float*)d_in[1];
  const float* emb = (const float*)d_in[2];
  const float* W1 = (const float*)d_in[3];
  const float* b1 = (const float*)d_in[4];
  const float* g1 = (const float*)d_in[5];
  const float* be1 = (const float*)d_in[6];
  const float* W2 = (const float*)d_in[7];
  const float* b2 = (const float*)d_in[8];
  const float* g2 = (const float*)d_in[9];
  const float* be2 = (const float*)d_in[10];
  const float* W3 = (const float*)d_in[11];
  const float* b3 = (const float*)d_in[12];
  const float* mw = (const float*)d_in[13];
  float* out = (float*)d_out;

  const int E = in_sizes[0] / 2;
  const int* src = edge;
  const int* dst = edge + E;
  const int NB = (NUM_NODES + 255) / 256;  // 274 scan blocks

  // workspace layout.
  //   [0 .. 40.96MB)      h1 (MLP hidden 1; alias meta; later alias scan arrays)
  //   [40.96 .. 51.2MB)   h2 (MLP hidden 2; later alias csr_src 8MB)
  //   [51.2 .. 87.04MB)   xA
  //   [87.04 .. 122.88MB) xB
  // Aliasing is safe: all kernels on one stream, lifetimes disjoint in order.
  char* ws = (char*)d_ws;
  float* h1 = (float*)(ws + 0);
  float* h2 = (float*)(ws + 40960000);
  float* xA = (float*)(ws + 51200000);
  float* xB = (float*)(ws + 87040000);
  float* meta = h1;  // h1 dead once gemm2 consumed it

  // graph arrays alias the (dead after build_e0) MLP buffers
  int* deg = (int*)(ws + 0);                 // 280 KB
  float* dinv = (float*)(ws + (1 << 20));    // 280 KB
  int* rowptr = (int*)(ws + (2 << 20));      // 280 KB (+1)
  int* cursor = (int*)(ws + (3 << 20));      // 280 KB
  int* bsum = (int*)(ws + (4 << 20));        // ~1.1 KB
  int* csr_src = (int*)(ws + 40960000);      // 8 MB (h2 region)

  // ---- item metadata MLP ----
  {
    dim3 g(H1DIM / 64, (NUM_ITEMS + 63) / 64);
    gemm_bias<<<g, 256, 0, stream>>>(item_feat, W1, b1, h1, NUM_ITEMS, H1DIM,
                                     FEAT_DIM);
  }
  ln_relu_w512<<<NUM_ITEMS, 256, 0, stream>>>(h1, g1, be1);
  {
    dim3 g(HID / 64, (NUM_ITEMS + 63) / 64);
    gemm_bias<<<g, 256, 0, stream>>>(h1, W2, b2, h2, NUM_ITEMS, HID, H1DIM);
  }
  ln_relu_w128<<<(NUM_ITEMS * 64 + 255) / 256, 256, 0, stream>>>(h2, g2, be2,
                                                                 NUM_ITEMS);
  gemm3_norm<<<NUM_ITEMS, 128, 0, stream>>>(h2, W3, b3, meta);

  // ---- e0 and out init (consumes meta; afterwards h1/h2 regions are free) ----
  build_e0<<<(NUM_NODES * HID) / 256, 256, 0, stream>>>(emb, meta, mw, xA, out);

  // ---- graph normalization + CSR build ----
  hipMemsetAsync(deg, 0, NUM_NODES * sizeof(int), stream);
  count_deg<<<(E + 255) / 256, 256, 0, stream>>>(dst, deg, E);
  calc_dinv<<<(NUM_NODES + 255) / 256, 256, 0, stream>>>(deg, dinv, NUM_NODES);
  scan1<<<NB, 256, 0, stream>>>(deg, rowptr, bsum, NUM_NODES);
  scan2<<<1, 64, 0, stream>>>(bsum, NB);
  scan3<<<NB, 256, 0, stream>>>(rowptr, bsum, NUM_NODES, E);
  hipMemcpyAsync(cursor, rowptr, NUM_NODES * sizeof(int),
                 hipMemcpyDeviceToDevice, stream);
  fill_csr<<<(E + 255) / 256, 256, 0, stream>>>(src, dst, cursor, csr_src, E);

  // ---- 3 propagation layers (gather, no atomics, fused axpy) ----
  float* xcur = xA;
  float* xnext = xB;
  for (int l = 0; l < 3; l++) {
    spmm_gather<<<(NUM_NODES * 64) / 256, 256, 0, stream>>>(rowptr, csr_src,
                                                            dinv, xcur, xnext,
                                                            out);
    float* tmp = xcur; xcur = xnext; xnext = tmp;
  }
}

// Round 4
// 952.821 us; speedup vs baseline: 11.1889x; 1.2541x over previous
//
#include <hip/hip_runtime.h>
#include <hip/hip_bf16.h>

// ---------------- constants ----------------
#define NUM_USERS 50000
#define NUM_ITEMS 20000
#define NUM_NODES (NUM_USERS + NUM_ITEMS)
#define FEAT_DIM 768
#define HID 128
#define H1DIM 512
#define LN_EPS 1e-5f
#define ALPHA 0.25f

typedef __attribute__((ext_vector_type(8))) short short8;
typedef __attribute__((ext_vector_type(4))) float floatx4;

// bf16 round-to-nearest-even (inputs are finite, no NaN handling needed)
static __device__ inline unsigned short f2bf(float f) {
  unsigned int u = __float_as_uint(f);
  u += 0x7fffu + ((u >> 16) & 1u);
  return (unsigned short)(u >> 16);
}

// -------- cast fp32 -> bf16, 8 elements/thread, exact grid -------------------
__global__ __launch_bounds__(256) void cast_bf16(
    const float* __restrict__ in, unsigned short* __restrict__ out) {
  size_t i = (size_t)blockIdx.x * 256 + threadIdx.x;
  float4 u = ((const float4*)in)[i * 2];
  float4 v = ((const float4*)in)[i * 2 + 1];
  union { unsigned short s[8]; uint4 q; } p;
  p.s[0] = f2bf(u.x); p.s[1] = f2bf(u.y); p.s[2] = f2bf(u.z); p.s[3] = f2bf(u.w);
  p.s[4] = f2bf(v.x); p.s[5] = f2bf(v.y); p.s[6] = f2bf(v.z); p.s[7] = f2bf(v.w);
  ((uint4*)out)[i] = p.q;
}

// -------- transpose+cast: W[K x N] fp32 -> Wt[N x K] bf16 --------------------
// block (32,8), grid (N/32, K/32)
__global__ __launch_bounds__(256) void transpose_cast(
    const float* __restrict__ W, unsigned short* __restrict__ Wt,
    int K, int N) {
  __shared__ float tile[32][33];
  int tx = threadIdx.x, ty = threadIdx.y;
  int bx = blockIdx.x, by = blockIdx.y;
#pragma unroll
  for (int kk = 0; kk < 4; kk++)
    tile[ty + kk * 8][tx] = W[(size_t)(by * 32 + ty + kk * 8) * N + bx * 32 + tx];
  __syncthreads();
#pragma unroll
  for (int kk = 0; kk < 4; kk++)
    Wt[(size_t)(bx * 32 + ty + kk * 8) * K + by * 32 + tx] =
        f2bf(tile[tx][ty + kk * 8]);
}

// -------- bf16 MFMA GEMM: C(MxN) fp32 = A(MxK) . Bt(NxK)^T + bias ------------
// BM=BN=128, BK=32, 256 threads = 4 waves, each wave 64x64 (4x4 MFMA 16x16x32).
// A, Bt are bf16 row-major with K contiguous. N multiple of 128, K mult of 32.
__global__ __launch_bounds__(256) void gemm_mfma_bias(
    const unsigned short* __restrict__ A, const unsigned short* __restrict__ Bt,
    const float* __restrict__ bias, float* __restrict__ C,
    int M, int N, int K) {
  __shared__ __align__(16) unsigned short As[128 * 32];
  __shared__ __align__(16) unsigned short Bs[128 * 32];
  const int tid = threadIdx.x;
  const int wave = tid >> 6, lane = tid & 63;
  const int quad = lane >> 4, l16 = lane & 15;
  const int wm = wave >> 1, wn = wave & 1;
  const int bm = blockIdx.y * 128, bn = blockIdx.x * 128;

  floatx4 acc[4][4];
#pragma unroll
  for (int i = 0; i < 4; i++)
#pragma unroll
    for (int j = 0; j < 4; j++) acc[i][j] = (floatx4){0.f, 0.f, 0.f, 0.f};

  // staging geometry: chunk = 16 rows x 32 bf16 = 1024B filled by one wave
  // (lds dest is wave-uniform base + lane*16B; lane covers row lane/4, 8 bf16)
  const int srow = lane >> 2;
  const int scol = (lane & 3) * 8;

  for (int k0 = 0; k0 < K; k0 += 32) {
#pragma unroll
    for (int i = 0; i < 2; i++) {
      int c = wave * 2 + i;
      int arow = bm + c * 16 + srow;
      if (arow >= M) arow = M - 1;  // clamp: garbage rows never stored
      const unsigned short* ga = A + (size_t)arow * K + k0 + scol;
      __builtin_amdgcn_global_load_lds(
          (const __attribute__((address_space(1))) unsigned int*)(uintptr_t)ga,
          (__attribute__((address_space(3))) unsigned int*)(uintptr_t)(As + c * 512),
          16, 0, 0);
      int brow = bn + c * 16 + srow;  // always < N (N % 128 == 0)
      const unsigned short* gb = Bt + (size_t)brow * K + k0 + scol;
      __builtin_amdgcn_global_load_lds(
          (const __attribute__((address_space(1))) unsigned int*)(uintptr_t)gb,
          (__attribute__((address_space(3))) unsigned int*)(uintptr_t)(Bs + c * 512),
          16, 0, 0);
    }
    __syncthreads();

    short8 af[4], bf[4];
#pragma unroll
    for (int i = 0; i < 4; i++) {
      af[i] = *(const short8*)&As[(wm * 64 + i * 16 + l16) * 32 + quad * 8];
      bf[i] = *(const short8*)&Bs[(wn * 64 + i * 16 + l16) * 32 + quad * 8];
    }
#pragma unroll
    for (int i = 0; i < 4; i++)
#pragma unroll
      for (int j = 0; j < 4; j++)
        acc[i][j] = __builtin_amdgcn_mfma_f32_16x16x32_bf16(af[i], bf[j],
                                                            acc[i][j], 0, 0, 0);
    __syncthreads();
  }

  // epilogue: D[row][col], col = lane&15, row = quad*4 + r
#pragma unroll
  for (int i = 0; i < 4; i++) {
    int row0 = bm + wm * 64 + i * 16 + quad * 4;
#pragma unroll
    for (int j = 0; j < 4; j++) {
      int col = bn + wn * 64 + j * 16 + l16;
      float bv = bias[col];
#pragma unroll
      for (int r = 0; r < 4; r++) {
        int row = row0 + r;
        if (row < M) C[(size_t)row * N + col] = acc[i][j][r] + bv;
      }
    }
  }
}

// ---- LayerNorm+ReLU width 512, fp32 in -> bf16 out, one block(256)/row ------
__global__ __launch_bounds__(256) void ln_relu_w512_bf16(
    const float* __restrict__ X, const float* __restrict__ g,
    const float* __restrict__ be, unsigned short* __restrict__ O) {
  int row = blockIdx.x, t = threadIdx.x;
  const float* x = X + (size_t)row * H1DIM;
  float v0 = x[t], v1 = x[t + 256];
  float s = v0 + v1, q = v0 * v0 + v1 * v1;
#pragma unroll
  for (int off = 32; off > 0; off >>= 1) {
    s += __shfl_down(s, off);
    q += __shfl_down(q, off);
  }
  __shared__ float ss[4], qq[4];
  int lane = t & 63, wid = t >> 6;
  if (lane == 0) { ss[wid] = s; qq[wid] = q; }
  __syncthreads();
  float S = ss[0] + ss[1] + ss[2] + ss[3];
  float Q = qq[0] + qq[1] + qq[2] + qq[3];
  float mu = S * (1.f / 512.f);
  float var = Q * (1.f / 512.f) - mu * mu;
  float rs = rsqrtf(var + LN_EPS);
  float y0 = (v0 - mu) * rs * g[t] + be[t];
  float y1 = (v1 - mu) * rs * g[t + 256] + be[t + 256];
  unsigned short* o = O + (size_t)row * H1DIM;
  o[t] = f2bf(fmaxf(y0, 0.f));
  o[t + 256] = f2bf(fmaxf(y1, 0.f));
}

// ---------------- LayerNorm+ReLU, width 128, one wave per row ----------------
__global__ __launch_bounds__(256) void ln_relu_w128(
    float* __restrict__ X, const float* __restrict__ g,
    const float* __restrict__ be, int rows) {
  int gwid = (blockIdx.x * blockDim.x + threadIdx.x) >> 6;
  if (gwid >= rows) return;
  int lane = threadIdx.x & 63;
  float* x = X + (size_t)gwid * HID;
  float v0 = x[lane], v1 = x[lane + 64];
  float s = v0 + v1, q = v0 * v0 + v1 * v1;
#pragma unroll
  for (int off = 32; off > 0; off >>= 1) {
    s += __shfl_down(s, off);
    q += __shfl_down(q, off);
  }
  s = __shfl(s, 0);
  q = __shfl(q, 0);
  float mu = s * (1.f / 128.f);
  float var = q * (1.f / 128.f) - mu * mu;
  float rs = rsqrtf(var + LN_EPS);
  float y0 = (v0 - mu) * rs * g[lane] + be[lane];
  float y1 = (v1 - mu) * rs * g[lane + 64] + be[lane + 64];
  x[lane] = fmaxf(y0, 0.f);
  x[lane + 64] = fmaxf(y1, 0.f);
}

// ---- GEMM3 (128x128) + L2-normalize, 4 rows/block (W3 loads shared x4) ------
__global__ __launch_bounds__(128) void gemm3_norm4(
    const float* __restrict__ H, const float* __restrict__ W3,
    const float* __restrict__ b3, float* __restrict__ meta) {
  int r0 = blockIdx.x * 4, t = threadIdx.x;
  __shared__ float hrow[4][HID];
#pragma unroll
  for (int r = 0; r < 4; r++) hrow[r][t] = H[(size_t)(r0 + r) * HID + t];
  __syncthreads();
  float s0 = 0.f, s1 = 0.f, s2 = 0.f, s3 = 0.f;
#pragma unroll 4
  for (int k = 0; k < HID; k++) {
    float w = W3[k * HID + t];
    s0 = fmaf(hrow[0][k], w, s0);
    s1 = fmaf(hrow[1][k], w, s1);
    s2 = fmaf(hrow[2][k], w, s2);
    s3 = fmaf(hrow[3][k], w, s3);
  }
  float b = b3[t];
  s0 += b; s1 += b; s2 += b; s3 += b;
  float q0 = s0 * s0, q1 = s1 * s1, q2 = s2 * s2, q3 = s3 * s3;
#pragma unroll
  for (int off = 32; off > 0; off >>= 1) {
    q0 += __shfl_down(q0, off);
    q1 += __shfl_down(q1, off);
    q2 += __shfl_down(q2, off);
    q3 += __shfl_down(q3, off);
  }
  __shared__ float qs[4][2];
  if ((t & 63) == 0) {
    int w = t >> 6;
    qs[0][w] = q0; qs[1][w] = q1; qs[2][w] = q2; qs[3][w] = q3;
  }
  __syncthreads();
  float n0 = fmaxf(sqrtf(qs[0][0] + qs[0][1]), 1e-12f);
  float n1 = fmaxf(sqrtf(qs[1][0] + qs[1][1]), 1e-12f);
  float n2 = fmaxf(sqrtf(qs[2][0] + qs[2][1]), 1e-12f);
  float n3 = fmaxf(sqrtf(qs[3][0] + qs[3][1]), 1e-12f);
  meta[(size_t)(r0 + 0) * HID + t] = s0 / n0;
  meta[(size_t)(r0 + 1) * HID + t] = s1 / n1;
  meta[(size_t)(r0 + 2) * HID + t] = s2 / n2;
  meta[(size_t)(r0 + 3) * HID + t] = s3 / n3;
}

// --------- build e0 = [emb_users; emb_items + mw*meta], out = alpha*e0 -------
__global__ __launch_bounds__(256) void build_e0(
    const float* __restrict__ emb, const float* __restrict__ meta,
    const float* __restrict__ mw_p, float* __restrict__ x0,
    float* __restrict__ out) {
  size_t i = (size_t)blockIdx.x * 256 + threadIdx.x;  // exact grid
  float e = emb[i];
  size_t node = i >> 7;
  if (node >= NUM_USERS) e += mw_p[0] * meta[i - (size_t)NUM_USERS * HID];
  x0[i] = e;
  out[i] = ALPHA * e;
}

// ---------------- degree count / dinv ----------------------------------------
__global__ __launch_bounds__(256) void count_deg(const int* __restrict__ dst,
                                                 int* __restrict__ deg, int E) {
  int e = blockIdx.x * 256 + threadIdx.x;
  if (e < E) atomicAdd(&deg[dst[e]], 1);
}

__global__ __launch_bounds__(256) void calc_dinv(const int* __restrict__ deg,
                                                 float* __restrict__ dinv, int n) {
  int i = blockIdx.x * 256 + threadIdx.x;
  if (i < n) dinv[i] = deg[i] > 0 ? rsqrtf((float)deg[i]) : 0.f;
}

// ---------------- exclusive scan (3-kernel, n=70000) -------------------------
__global__ __launch_bounds__(256) void scan1(const int* __restrict__ deg,
                                             int* __restrict__ rowptr,
                                             int* __restrict__ bsum, int n) {
  int i = blockIdx.x * 256 + threadIdx.x;
  int v = (i < n) ? deg[i] : 0;
  int lane = threadIdx.x & 63, wid = threadIdx.x >> 6;
  int s = v;
#pragma unroll
  for (int off = 1; off < 64; off <<= 1) {
    int t = __shfl_up(s, off);
    if (lane >= off) s += t;
  }
  __shared__ int wsum[4];
  if (lane == 63) wsum[wid] = s;
  __syncthreads();
  int add = 0;
  for (int w = 0; w < wid; w++) add += wsum[w];
  int incl = s + add;
  if (i < n) rowptr[i] = incl - v;  // exclusive
  if (threadIdx.x == 255) bsum[blockIdx.x] = incl;  // block total
}

// block-parallel scan over <=512 block sums (was serial single-thread)
__global__ __launch_bounds__(512) void scan2(int* __restrict__ bsum, int nb) {
  int t = threadIdx.x;
  int v = (t < nb) ? bsum[t] : 0;
  int lane = t & 63, wid = t >> 6;
  int s = v;
#pragma unroll
  for (int off = 1; off < 64; off <<= 1) {
    int u = __shfl_up(s, off);
    if (lane >= off) s += u;
  }
  __shared__ int ws[8];
  if (lane == 63) ws[wid] = s;
  __syncthreads();
  int add = 0;
  for (int w = 0; w < wid; w++) add += ws[w];
  if (t < nb) bsum[t] = s + add - v;  // exclusive
}

__global__ __launch_bounds__(256) void scan3(int* __restrict__ rowptr,
                                             const int* __restrict__ bsum,
                                             int n, int E) {
  int i = blockIdx.x * 256 + threadIdx.x;
  if (i < n) rowptr[i] += bsum[blockIdx.x];
  if (i == 0) rowptr[n] = E;
}

// ---------------- CSR fill ---------------------------------------------------
__global__ __launch_bounds__(256) void fill_csr(const int* __restrict__ src,
                                                const int* __restrict__ dst,
                                                int* __restrict__ cursor,
                                                int* __restrict__ csr_src,
                                                int E) {
  int e = blockIdx.x * 256 + threadIdx.x;
  if (e < E) {
    int pos = atomicAdd(&cursor[dst[e]], 1);
    csr_src[pos] = src[e];
  }
}

// ---------------- SpMM gather v2: 2 rows/wave, float4/lane, unroll 4 ---------
// y[row] = dinv[row] * sum dinv[s]*x[s];  out[row] += alpha*y[row]
__global__ __launch_bounds__(256) void spmm_gather4(
    const int* __restrict__ rowptr, const int* __restrict__ csr_src,
    const float* __restrict__ dinv, const float* __restrict__ x,
    float* __restrict__ y, float* __restrict__ out, int write_y) {
  int wid = (blockIdx.x * 256 + threadIdx.x) >> 6;
  int lane = threadIdx.x & 63;
  int half = lane >> 5, q = lane & 31;
  int row = wid * 2 + half;  // exact: grid covers 70000 rows
  int beg = rowptr[row], end = rowptr[row + 1];
  float wd = dinv[row];
  float ax = 0.f, ay = 0.f, az = 0.f, aw = 0.f;
  const float* xq = x + q * 4;
  int p = beg;
  for (; p + 4 <= end; p += 4) {
    int s0 = csr_src[p], s1 = csr_src[p + 1];
    int s2 = csr_src[p + 2], s3 = csr_src[p + 3];
    float c0 = dinv[s0], c1 = dinv[s1], c2 = dinv[s2], c3 = dinv[s3];
    float4 v0 = *(const float4*)(xq + (size_t)s0 * HID);
    float4 v1 = *(const float4*)(xq + (size_t)s1 * HID);
    float4 v2 = *(const float4*)(xq + (size_t)s2 * HID);
    float4 v3 = *(const float4*)(xq + (size_t)s3 * HID);
    ax += c0 * v0.x + c1 * v1.x + c2 * v2.x + c3 * v3.x;
    ay += c0 * v0.y + c1 * v1.y + c2 * v2.y + c3 * v3.y;
    az += c0 * v0.z + c1 * v1.z + c2 * v2.z + c3 * v3.z;
    aw += c0 * v0.w + c1 * v1.w + c2 * v2.w + c3 * v3.w;
  }
  for (; p < end; p++) {
    int s0 = csr_src[p];
    float c0 = dinv[s0];
    float4 v0 = *(const float4*)(xq + (size_t)s0 * HID);
    ax += c0 * v0.x; ay += c0 * v0.y; az += c0 * v0.z; aw += c0 * v0.w;
  }
  float4 res = make_float4(wd * ax, wd * ay, wd * az, wd * aw);
  size_t o = (size_t)row * HID + q * 4;
  if (write_y) *(float4*)&y[o] = res;
  float4 po = *(const float4*)&out[o];
  po.x += ALPHA * res.x; po.y += ALPHA * res.y;
  po.z += ALPHA * res.z; po.w += ALPHA * res.w;
  *(float4*)&out[o] = po;
}

// ---------------- launcher ---------------------------------------------------
extern "C" void kernel_launch(void* const* d_in, const int* in_sizes, int n_in,
                              void* d_out, int out_size, void* d_ws,
                              size_t ws_size, hipStream_t stream) {
  const int* edge = (const int*)d_in[0];
  const float* item_feat = (const float*)d_in[1];
  const float* emb = (const float*)d_in[2];
  const float* W1 = (const float*)d_in[3];
  const float* b1 = (const float*)d_in[4];
  const float* g1 = (const float*)d_in[5];
  const float* be1 = (const float*)d_in[6];
  const float* W2 = (const float*)d_in[7];
  const float* b2 = (const float*)d_in[8];
  const float* g2 = (const float*)d_in[9];
  const float* be2 = (const float*)d_in[10];
  const float* W3 = (const float*)d_in[11];
  const float* b3 = (const float*)d_in[12];
  const float* mw = (const float*)d_in[13];
  float* out = (float*)d_out;

  const int E = in_sizes[0] / 2;
  const int* src = edge;
  const int* dst = edge + E;
  const int NB = (NUM_NODES + 255) / 256;  // 274

  // workspace layout (lifetimes disjoint, single stream):
  //  [0, 40.96M)        h1 fp32 -> meta (10.24M) -> deg/dinv/rowptr/cursor/bsum
  //  [40.96M, 51.2M)    h2 fp32 -> csr_src (8M)
  //  [51.2M, 87.04M)    h1b bf16 (20.48M) -> xA
  //  [87.04M, 122.88M)  Af bf16 (30.72M) -> xB
  //  [122.88M, 123.8M)  W1t, W2t bf16
  char* ws = (char*)d_ws;
  float* h1 = (float*)(ws + 0);
  float* h2 = (float*)(ws + 40960000);
  unsigned short* h1b = (unsigned short*)(ws + 51200000);
  float* xA = (float*)(ws + 51200000);
  unsigned short* Af = (unsigned short*)(ws + 87040000);
  float* xB = (float*)(ws + 87040000);
  unsigned short* W1t = (unsigned short*)(ws + 122880000);
  unsigned short* W2t = (unsigned short*)(ws + 123666432);
  float* meta = h1;

  int* deg = (int*)(ws + 0);
  float* dinv = (float*)(ws + (1 << 20));
  int* rowptr = (int*)(ws + (2 << 20));
  int* cursor = (int*)(ws + (3 << 20));
  int* bsum = (int*)(ws + (4 << 20));
  int* csr_src = (int*)(ws + 40960000);

  // ---- casts ----
  cast_bf16<<<(NUM_ITEMS * FEAT_DIM / 8) / 256, 256, 0, stream>>>(item_feat, Af);
  transpose_cast<<<dim3(H1DIM / 32, FEAT_DIM / 32), dim3(32, 8), 0, stream>>>(
      W1, W1t, FEAT_DIM, H1DIM);
  transpose_cast<<<dim3(HID / 32, H1DIM / 32), dim3(32, 8), 0, stream>>>(
      W2, W2t, H1DIM, HID);

  // ---- item metadata MLP (bf16 MFMA GEMMs) ----
  gemm_mfma_bias<<<dim3(H1DIM / 128, (NUM_ITEMS + 127) / 128), 256, 0, stream>>>(
      Af, W1t, b1, h1, NUM_ITEMS, H1DIM, FEAT_DIM);
  ln_relu_w512_bf16<<<NUM_ITEMS, 256, 0, stream>>>(h1, g1, be1, h1b);
  gemm_mfma_bias<<<dim3(HID / 128, (NUM_ITEMS + 127) / 128), 256, 0, stream>>>(
      h1b, W2t, b2, h2, NUM_ITEMS, HID, H1DIM);
  ln_relu_w128<<<(NUM_ITEMS * 64) / 256, 256, 0, stream>>>(h2, g2, be2,
                                                           NUM_ITEMS);
  gemm3_norm4<<<NUM_ITEMS / 4, 128, 0, stream>>>(h2, W3, b3, meta);

  // ---- e0 and out init ----
  build_e0<<<(NUM_NODES * HID) / 256, 256, 0, stream>>>(emb, meta, mw, xA, out);

  // ---- graph normalization + CSR build ----
  hipMemsetAsync(deg, 0, NUM_NODES * sizeof(int), stream);
  count_deg<<<(E + 255) / 256, 256, 0, stream>>>(dst, deg, E);
  calc_dinv<<<(NUM_NODES + 255) / 256, 256, 0, stream>>>(deg, dinv, NUM_NODES);
  scan1<<<NB, 256, 0, stream>>>(deg, rowptr, bsum, NUM_NODES);
  scan2<<<1, 512, 0, stream>>>(bsum, NB);
  scan3<<<NB, 256, 0, stream>>>(rowptr, bsum, NUM_NODES, E);
  hipMemcpyAsync(cursor, rowptr, NUM_NODES * sizeof(int),
                 hipMemcpyDeviceToDevice, stream);
  fill_csr<<<(E + 255) / 256, 256, 0, stream>>>(src, dst, cursor, csr_src, E);

  // ---- 3 propagation layers ----
  spmm_gather4<<<(NUM_NODES / 2 * 64) / 256, 256, 0, stream>>>(
      rowptr, csr_src, dinv, xA, xB, out, 1);
  spmm_gather4<<<(NUM_NODES / 2 * 64) / 256, 256, 0, stream>>>(
      rowptr, csr_src, dinv, xB, xA, out, 1);
  spmm_gather4<<<(NUM_NODES / 2 * 64) / 256, 256, 0, stream>>>(
      rowptr, csr_src, dinv, xA, xB, out, 0);
}

// Round 5
// 651.070 us; speedup vs baseline: 16.3746x; 1.4635x over previous
//
#include <hip/hip_runtime.h>
#include <hip/hip_bf16.h>

// ---------------- constants ----------------
#define NUM_USERS 50000
#define NUM_ITEMS 20000
#define NUM_NODES (NUM_USERS + NUM_ITEMS)
#define FEAT_DIM 768
#define HID 128
#define H1DIM 512
#define LN_EPS 1e-5f
#define ALPHA 0.25f
#define NBKT 137  // ceil(70000/512) coarse buckets

typedef __attribute__((ext_vector_type(8))) short short8;
typedef __attribute__((ext_vector_type(4))) float floatx4;

// bf16 round-to-nearest-even
static __device__ inline unsigned short f2bf(float f) {
  unsigned int u = __float_as_uint(f);
  u += 0x7fffu + ((u >> 16) & 1u);
  return (unsigned short)(u >> 16);
}
static __device__ inline float bflo(unsigned int u) {
  return __uint_as_float(u << 16);
}
static __device__ inline float bfhi(unsigned int u) {
  return __uint_as_float(u & 0xffff0000u);
}

// -------- cast fp32 -> bf16, 8 elements/thread, exact grid -------------------
__global__ __launch_bounds__(256) void cast_bf16(
    const float* __restrict__ in, unsigned short* __restrict__ out) {
  size_t i = (size_t)blockIdx.x * 256 + threadIdx.x;
  float4 u = ((const float4*)in)[i * 2];
  float4 v = ((const float4*)in)[i * 2 + 1];
  union { unsigned short s[8]; uint4 q; } p;
  p.s[0] = f2bf(u.x); p.s[1] = f2bf(u.y); p.s[2] = f2bf(u.z); p.s[3] = f2bf(u.w);
  p.s[4] = f2bf(v.x); p.s[5] = f2bf(v.y); p.s[6] = f2bf(v.z); p.s[7] = f2bf(v.w);
  ((uint4*)out)[i] = p.q;
}

// -------- transpose+cast: W[K x N] fp32 -> Wt[N x K] bf16 --------------------
__global__ __launch_bounds__(256) void transpose_cast(
    const float* __restrict__ W, unsigned short* __restrict__ Wt,
    int K, int N) {
  __shared__ float tile[32][33];
  int tx = threadIdx.x, ty = threadIdx.y;
  int bx = blockIdx.x, by = blockIdx.y;
#pragma unroll
  for (int kk = 0; kk < 4; kk++)
    tile[ty + kk * 8][tx] = W[(size_t)(by * 32 + ty + kk * 8) * N + bx * 32 + tx];
  __syncthreads();
#pragma unroll
  for (int kk = 0; kk < 4; kk++)
    Wt[(size_t)(bx * 32 + ty + kk * 8) * K + by * 32 + tx] =
        f2bf(tile[tx][ty + kk * 8]);
}

// -------- bf16 MFMA GEMM: C(MxN) fp32 = A(MxK) . Bt(NxK)^T + bias ------------
__global__ __launch_bounds__(256) void gemm_mfma_bias(
    const unsigned short* __restrict__ A, const unsigned short* __restrict__ Bt,
    const float* __restrict__ bias, float* __restrict__ C,
    int M, int N, int K) {
  __shared__ __align__(16) unsigned short As[128 * 32];
  __shared__ __align__(16) unsigned short Bs[128 * 32];
  const int tid = threadIdx.x;
  const int wave = tid >> 6, lane = tid & 63;
  const int quad = lane >> 4, l16 = lane & 15;
  const int wm = wave >> 1, wn = wave & 1;
  const int bm = blockIdx.y * 128, bn = blockIdx.x * 128;

  floatx4 acc[4][4];
#pragma unroll
  for (int i = 0; i < 4; i++)
#pragma unroll
    for (int j = 0; j < 4; j++) acc[i][j] = (floatx4){0.f, 0.f, 0.f, 0.f};

  const int srow = lane >> 2;
  const int scol = (lane & 3) * 8;

  for (int k0 = 0; k0 < K; k0 += 32) {
#pragma unroll
    for (int i = 0; i < 2; i++) {
      int c = wave * 2 + i;
      int arow = bm + c * 16 + srow;
      if (arow >= M) arow = M - 1;
      const unsigned short* ga = A + (size_t)arow * K + k0 + scol;
      __builtin_amdgcn_global_load_lds(
          (const __attribute__((address_space(1))) unsigned int*)(uintptr_t)ga,
          (__attribute__((address_space(3))) unsigned int*)(uintptr_t)(As + c * 512),
          16, 0, 0);
      int brow = bn + c * 16 + srow;
      const unsigned short* gb = Bt + (size_t)brow * K + k0 + scol;
      __builtin_amdgcn_global_load_lds(
          (const __attribute__((address_space(1))) unsigned int*)(uintptr_t)gb,
          (__attribute__((address_space(3))) unsigned int*)(uintptr_t)(Bs + c * 512),
          16, 0, 0);
    }
    __syncthreads();

    short8 af[4], bf[4];
#pragma unroll
    for (int i = 0; i < 4; i++) {
      af[i] = *(const short8*)&As[(wm * 64 + i * 16 + l16) * 32 + quad * 8];
      bf[i] = *(const short8*)&Bs[(wn * 64 + i * 16 + l16) * 32 + quad * 8];
    }
#pragma unroll
    for (int i = 0; i < 4; i++)
#pragma unroll
      for (int j = 0; j < 4; j++)
        acc[i][j] = __builtin_amdgcn_mfma_f32_16x16x32_bf16(af[i], bf[j],
                                                            acc[i][j], 0, 0, 0);
    __syncthreads();
  }

#pragma unroll
  for (int i = 0; i < 4; i++) {
    int row0 = bm + wm * 64 + i * 16 + quad * 4;
#pragma unroll
    for (int j = 0; j < 4; j++) {
      int col = bn + wn * 64 + j * 16 + l16;
      float bv = bias[col];
#pragma unroll
      for (int r = 0; r < 4; r++) {
        int row = row0 + r;
        if (row < M) C[(size_t)row * N + col] = acc[i][j][r] + bv;
      }
    }
  }
}

// ---- LayerNorm+ReLU width 512, fp32 in -> bf16 out --------------------------
__global__ __launch_bounds__(256) void ln_relu_w512_bf16(
    const float* __restrict__ X, const float* __restrict__ g,
    const float* __restrict__ be, unsigned short* __restrict__ O) {
  int row = blockIdx.x, t = threadIdx.x;
  const float* x = X + (size_t)row * H1DIM;
  float v0 = x[t], v1 = x[t + 256];
  float s = v0 + v1, q = v0 * v0 + v1 * v1;
#pragma unroll
  for (int off = 32; off > 0; off >>= 1) {
    s += __shfl_down(s, off);
    q += __shfl_down(q, off);
  }
  __shared__ float ss[4], qq[4];
  int lane = t & 63, wid = t >> 6;
  if (lane == 0) { ss[wid] = s; qq[wid] = q; }
  __syncthreads();
  float S = ss[0] + ss[1] + ss[2] + ss[3];
  float Q = qq[0] + qq[1] + qq[2] + qq[3];
  float mu = S * (1.f / 512.f);
  float var = Q * (1.f / 512.f) - mu * mu;
  float rs = rsqrtf(var + LN_EPS);
  float y0 = (v0 - mu) * rs * g[t] + be[t];
  float y1 = (v1 - mu) * rs * g[t + 256] + be[t + 256];
  unsigned short* o = O + (size_t)row * H1DIM;
  o[t] = f2bf(fmaxf(y0, 0.f));
  o[t + 256] = f2bf(fmaxf(y1, 0.f));
}

// ---------------- LayerNorm+ReLU, width 128, one wave per row ----------------
__global__ __launch_bounds__(256) void ln_relu_w128(
    float* __restrict__ X, const float* __restrict__ g,
    const float* __restrict__ be, int rows) {
  int gwid = (blockIdx.x * blockDim.x + threadIdx.x) >> 6;
  if (gwid >= rows) return;
  int lane = threadIdx.x & 63;
  float* x = X + (size_t)gwid * HID;
  float v0 = x[lane], v1 = x[lane + 64];
  float s = v0 + v1, q = v0 * v0 + v1 * v1;
#pragma unroll
  for (int off = 32; off > 0; off >>= 1) {
    s += __shfl_down(s, off);
    q += __shfl_down(q, off);
  }
  s = __shfl(s, 0);
  q = __shfl(q, 0);
  float mu = s * (1.f / 128.f);
  float var = q * (1.f / 128.f) - mu * mu;
  float rs = rsqrtf(var + LN_EPS);
  float y0 = (v0 - mu) * rs * g[lane] + be[lane];
  float y1 = (v1 - mu) * rs * g[lane + 64] + be[lane + 64];
  x[lane] = fmaxf(y0, 0.f);
  x[lane + 64] = fmaxf(y1, 0.f);
}

// ---- GEMM3 (128x128) + L2-normalize, 4 rows/block ---------------------------
__global__ __launch_bounds__(128) void gemm3_norm4(
    const float* __restrict__ H, const float* __restrict__ W3,
    const float* __restrict__ b3, float* __restrict__ meta) {
  int r0 = blockIdx.x * 4, t = threadIdx.x;
  __shared__ float hrow[4][HID];
#pragma unroll
  for (int r = 0; r < 4; r++) hrow[r][t] = H[(size_t)(r0 + r) * HID + t];
  __syncthreads();
  float s0 = 0.f, s1 = 0.f, s2 = 0.f, s3 = 0.f;
#pragma unroll 4
  for (int k = 0; k < HID; k++) {
    float w = W3[k * HID + t];
    s0 = fmaf(hrow[0][k], w, s0);
    s1 = fmaf(hrow[1][k], w, s1);
    s2 = fmaf(hrow[2][k], w, s2);
    s3 = fmaf(hrow[3][k], w, s3);
  }
  float b = b3[t];
  s0 += b; s1 += b; s2 += b; s3 += b;
  float q0 = s0 * s0, q1 = s1 * s1, q2 = s2 * s2, q3 = s3 * s3;
#pragma unroll
  for (int off = 32; off > 0; off >>= 1) {
    q0 += __shfl_down(q0, off);
    q1 += __shfl_down(q1, off);
    q2 += __shfl_down(q2, off);
    q3 += __shfl_down(q3, off);
  }
  __shared__ float qs[4][2];
  if ((t & 63) == 0) {
    int w = t >> 6;
    qs[0][w] = q0; qs[1][w] = q1; qs[2][w] = q2; qs[3][w] = q3;
  }
  __syncthreads();
  float n0 = fmaxf(sqrtf(qs[0][0] + qs[0][1]), 1e-12f);
  float n1 = fmaxf(sqrtf(qs[1][0] + qs[1][1]), 1e-12f);
  float n2 = fmaxf(sqrtf(qs[2][0] + qs[2][1]), 1e-12f);
  float n3 = fmaxf(sqrtf(qs[3][0] + qs[3][1]), 1e-12f);
  meta[(size_t)(r0 + 0) * HID + t] = s0 / n0;
  meta[(size_t)(r0 + 1) * HID + t] = s1 / n1;
  meta[(size_t)(r0 + 2) * HID + t] = s2 / n2;
  meta[(size_t)(r0 + 3) * HID + t] = s3 / n3;
}

// --------- build e0: x0 fp32, out = alpha*e0 ---------------------------------
__global__ __launch_bounds__(256) void build_e0(
    const float* __restrict__ emb, const float* __restrict__ meta,
    const float* __restrict__ mw_p, float* __restrict__ x0,
    float* __restrict__ out) {
  size_t i = (size_t)blockIdx.x * 256 + threadIdx.x;  // exact grid
  float e = emb[i];
  size_t node = i >> 7;
  if (node >= NUM_USERS) e += mw_p[0] * meta[i - (size_t)NUM_USERS * HID];
  x0[i] = e;
  out[i] = ALPHA * e;
}

// ======== atomic-free CSR build: two-level bucket sort =======================
// P1: coarse histogram over dst>>9 (137 buckets), per-block LDS hist
__global__ __launch_bounds__(256) void p1_hist(const int* __restrict__ dst,
                                               int* __restrict__ ghist,
                                               int E, int NBL) {
  __shared__ int h[NBKT];
  int t = threadIdx.x;
  if (t < NBKT) h[t] = 0;
  __syncthreads();
  int base = blockIdx.x * 8192;
  for (int i = t; i < 8192; i += 256) {
    int e = base + i;
    if (e < E) atomicAdd(&h[dst[e] >> 9], 1);
  }
  __syncthreads();
  if (t < NBKT) ghist[t * NBL + blockIdx.x] = h[t];
}

// generic exclusive scan (3 kernels), n <= 512*256*... (NB<=512)
__global__ __launch_bounds__(256) void scan_a(const int* __restrict__ in,
                                              int* __restrict__ outp,
                                              int* __restrict__ bsum, int n) {
  int i = blockIdx.x * 256 + threadIdx.x;
  int v = (i < n) ? in[i] : 0;
  int lane = threadIdx.x & 63, wid = threadIdx.x >> 6;
  int s = v;
#pragma unroll
  for (int off = 1; off < 64; off <<= 1) {
    int u = __shfl_up(s, off);
    if (lane >= off) s += u;
  }
  __shared__ int wsum[4];
  if (lane == 63) wsum[wid] = s;
  __syncthreads();
  int add = 0;
  for (int w = 0; w < wid; w++) add += wsum[w];
  int incl = s + add;
  if (i < n) outp[i] = incl - v;
  if (threadIdx.x == 255) bsum[blockIdx.x] = incl;
}

__global__ __launch_bounds__(512) void scan_b(int* __restrict__ bsum, int nb) {
  int t = threadIdx.x;
  int v = (t < nb) ? bsum[t] : 0;
  int lane = t & 63, wid = t >> 6;
  int s = v;
#pragma unroll
  for (int off = 1; off < 64; off <<= 1) {
    int u = __shfl_up(s, off);
    if (lane >= off) s += u;
  }
  __shared__ int ws[8];
  if (lane == 63) ws[wid] = s;
  __syncthreads();
  int add = 0;
  for (int w = 0; w < wid; w++) add += ws[w];
  if (t < nb) bsum[t] = s + add - v;
}

__global__ __launch_bounds__(256) void scan_c(int* __restrict__ outp,
                                              const int* __restrict__ bsum,
                                              int n) {
  int i = blockIdx.x * 256 + threadIdx.x;
  if (i < n) outp[i] += bsum[blockIdx.x];
}

// P1 scatter: (dst,src) pairs into bucket-contiguous regions, LDS cursors only
__global__ __launch_bounds__(256) void p1_scatter(
    const int* __restrict__ src, const int* __restrict__ dst,
    const int* __restrict__ gscan, unsigned long long* __restrict__ pairs,
    int E, int NBL) {
  __shared__ int cur[NBKT];
  int t = threadIdx.x;
  if (t < NBKT) cur[t] = gscan[t * NBL + blockIdx.x];
  __syncthreads();
  int base = blockIdx.x * 8192;
  for (int i = t; i < 8192; i += 256) {
    int e = base + i;
    if (e < E) {
      int d = dst[e];
      int pos = atomicAdd(&cur[d >> 9], 1);
      pairs[pos] = ((unsigned long long)(unsigned)d << 32) | (unsigned)src[e];
    }
  }
}

// P2: per-bucket fine sort (512 bins), writes rowptr + csr_src. 512 threads.
__global__ __launch_bounds__(512) void p2_build(
    const unsigned long long* __restrict__ pairs,
    const int* __restrict__ gscan, int* __restrict__ rowptr,
    int* __restrict__ csr_src, int E, int NBL) {
  __shared__ int hist[512];
  __shared__ int ws8[8];
  int b = blockIdx.x, t = threadIdx.x;
  int base = gscan[b * NBL];
  int end = (b == NBKT - 1) ? E : gscan[(b + 1) * NBL];
  hist[t] = 0;
  __syncthreads();
  for (int i = base + t; i < end; i += 512) {
    unsigned d = (unsigned)(pairs[i] >> 32);
    atomicAdd(&hist[d & 511], 1);
  }
  __syncthreads();
  // exclusive scan over 512 bins
  int v = hist[t];
  int lane = t & 63, wid = t >> 6;
  int s = v;
#pragma unroll
  for (int off = 1; off < 64; off <<= 1) {
    int u = __shfl_up(s, off);
    if (lane >= off) s += u;
  }
  if (lane == 63) ws8[wid] = s;
  __syncthreads();
  int add = 0;
  for (int w = 0; w < wid; w++) add += ws8[w];
  int excl = s + add - v;
  int node = (b << 9) + t;
  if (node < NUM_NODES) rowptr[node] = base + excl;
  if (b == NBKT - 1 && t == 0) rowptr[NUM_NODES] = E;
  __syncthreads();  // everyone has read hist -> reuse as cursor
  hist[t] = base + excl;
  __syncthreads();
  for (int i = base + t; i < end; i += 512) {
    unsigned long long p = pairs[i];
    unsigned d = (unsigned)(p >> 32);
    int pos = atomicAdd(&hist[d & 511], 1);
    csr_src[pos] = (int)(unsigned)p;
  }
}

// dinv from rowptr diff
__global__ __launch_bounds__(256) void calc_dinv2(const int* __restrict__ rowptr,
                                                  float* __restrict__ dinv,
                                                  int n) {
  int i = blockIdx.x * 256 + threadIdx.x;
  if (i < n) {
    int d = rowptr[i + 1] - rowptr[i];
    dinv[i] = d > 0 ? rsqrtf((float)d) : 0.f;
  }
}

// ---------------- SpMM gather: 2 rows/wave, 32 lanes x 4 feats ---------------
// XBF: 0 = x fp32 (layer 1), 1 = x bf16. y stored bf16, out fp32 RMW.
template <int XBF>
__global__ __launch_bounds__(256) void spmm_prop(
    const int* __restrict__ rowptr, const int* __restrict__ csr_src,
    const float* __restrict__ dinv, const void* __restrict__ xv,
    unsigned short* __restrict__ y, float* __restrict__ out, int write_y) {
  int wid = (blockIdx.x * 256 + threadIdx.x) >> 6;
  int lane = threadIdx.x & 63;
  int half = lane >> 5, q = lane & 31;
  int row = wid * 2 + half;  // exact grid: 70000 rows
  int beg = rowptr[row], end = rowptr[row + 1];
  float wd = dinv[row];
  float a0 = 0.f, a1 = 0.f, a2 = 0.f, a3 = 0.f;
  int p = beg;
  if (XBF) {
    const unsigned short* xq = (const unsigned short*)xv + q * 4;
    for (; p + 4 <= end; p += 4) {
      int s0 = csr_src[p], s1 = csr_src[p + 1];
      int s2 = csr_src[p + 2], s3 = csr_src[p + 3];
      float c0 = dinv[s0], c1 = dinv[s1], c2 = dinv[s2], c3 = dinv[s3];
      uint2 v0 = *(const uint2*)(xq + (size_t)s0 * HID);
      uint2 v1 = *(const uint2*)(xq + (size_t)s1 * HID);
      uint2 v2 = *(const uint2*)(xq + (size_t)s2 * HID);
      uint2 v3 = *(const uint2*)(xq + (size_t)s3 * HID);
      a0 += c0 * bflo(v0.x) + c1 * bflo(v1.x) + c2 * bflo(v2.x) + c3 * bflo(v3.x);
      a1 += c0 * bfhi(v0.x) + c1 * bfhi(v1.x) + c2 * bfhi(v2.x) + c3 * bfhi(v3.x);
      a2 += c0 * bflo(v0.y) + c1 * bflo(v1.y) + c2 * bflo(v2.y) + c3 * bflo(v3.y);
      a3 += c0 * bfhi(v0.y) + c1 * bfhi(v1.y) + c2 * bfhi(v2.y) + c3 * bfhi(v3.y);
    }
    for (; p < end; p++) {
      int s0 = csr_src[p];
      float c0 = dinv[s0];
      uint2 v0 = *(const uint2*)(xq + (size_t)s0 * HID);
      a0 += c0 * bflo(v0.x); a1 += c0 * bfhi(v0.x);
      a2 += c0 * bflo(v0.y); a3 += c0 * bfhi(v0.y);
    }
  } else {
    const float* xq = (const float*)xv + q * 4;
    for (; p + 4 <= end; p += 4) {
      int s0 = csr_src[p], s1 = csr_src[p + 1];
      int s2 = csr_src[p + 2], s3 = csr_src[p + 3];
      float c0 = dinv[s0], c1 = dinv[s1], c2 = dinv[s2], c3 = dinv[s3];
      float4 v0 = *(const float4*)(xq + (size_t)s0 * HID);
      float4 v1 = *(const float4*)(xq + (size_t)s1 * HID);
      float4 v2 = *(const float4*)(xq + (size_t)s2 * HID);
      float4 v3 = *(const float4*)(xq + (size_t)s3 * HID);
      a0 += c0 * v0.x + c1 * v1.x + c2 * v2.x + c3 * v3.x;
      a1 += c0 * v0.y + c1 * v1.y + c2 * v2.y + c3 * v3.y;
      a2 += c0 * v0.z + c1 * v1.z + c2 * v2.z + c3 * v3.z;
      a3 += c0 * v0.w + c1 * v1.w + c2 * v2.w + c3 * v3.w;
    }
    for (; p < end; p++) {
      int s0 = csr_src[p];
      float c0 = dinv[s0];
      float4 v0 = *(const float4*)(xq + (size_t)s0 * HID);
      a0 += c0 * v0.x; a1 += c0 * v0.y; a2 += c0 * v0.z; a3 += c0 * v0.w;
    }
  }
  a0 *= wd; a1 *= wd; a2 *= wd; a3 *= wd;
  size_t o = (size_t)row * HID + q * 4;
  if (write_y) {
    union { unsigned short s[4]; uint2 u; } pk;
    pk.s[0] = f2bf(a0); pk.s[1] = f2bf(a1);
    pk.s[2] = f2bf(a2); pk.s[3] = f2bf(a3);
    *(uint2*)&y[o] = pk.u;
  }
  float4 po = *(const float4*)&out[o];
  po.x += ALPHA * a0; po.y += ALPHA * a1;
  po.z += ALPHA * a2; po.w += ALPHA * a3;
  *(float4*)&out[o] = po;
}

// ---------------- launcher ---------------------------------------------------
extern "C" void kernel_launch(void* const* d_in, const int* in_sizes, int n_in,
                              void* d_out, int out_size, void* d_ws,
                              size_t ws_size, hipStream_t stream) {
  const int* edge = (const int*)d_in[0];
  const float* item_feat = (const float*)d_in[1];
  const float* emb = (const float*)d_in[2];
  const float* W1 = (const float*)d_in[3];
  const float* b1 = (const float*)d_in[4];
  const float* g1 = (const float*)d_in[5];
  const float* be1 = (const float*)d_in[6];
  const float* W2 = (const float*)d_in[7];
  const float* b2 = (const float*)d_in[8];
  const float* g2 = (const float*)d_in[9];
  const float* be2 = (const float*)d_in[10];
  const float* W3 = (const float*)d_in[11];
  const float* b3 = (const float*)d_in[12];
  const float* mw = (const float*)d_in[13];
  float* out = (float*)d_out;

  const int E = in_sizes[0] / 2;
  const int* src = edge;
  const int* dst = edge + E;
  const int NBL = (E + 8191) / 8192;        // 245 P1 blocks
  const int nScan = NBKT * NBL;             // 33565
  const int NBs = (nScan + 255) / 256;      // 132 <= 512

  // workspace layout (lifetimes disjoint on the single stream):
  //  [0, 40.96M)        h1 fp32 (meta aliases [0,10.24M)); after build_e0:
  //                       pairs@0 (16M), rowptr@16M, dinv@16.5M, ghist@16.8M,
  //                       gscan@17M, bsum@17.2M, csr_src@17.5M (8M)
  //  [40.96M, 51.2M)    h2 fp32
  //  [51.2M, 71.68M)    h1b bf16; after gemm2: xAf fp32 spans [51.2M, 87.04M)
  //  [87.04M, 117.76M)  Af bf16; after gemm1: xBb bf16 [87.04M,104.96M),
  //                       xCb bf16 [104.96M,122.88M)
  //  [122.88M, ...)     W1t, W2t bf16
  char* ws = (char*)d_ws;
  float* h1 = (float*)(ws + 0);
  float* h2 = (float*)(ws + 40960000);
  unsigned short* h1b = (unsigned short*)(ws + 51200000);
  float* xAf = (float*)(ws + 51200000);
  unsigned short* Af = (unsigned short*)(ws + 87040000);
  unsigned short* xBb = (unsigned short*)(ws + 87040000);
  unsigned short* xCb = (unsigned short*)(ws + 104960000);
  unsigned short* W1t = (unsigned short*)(ws + 122880000);
  unsigned short* W2t = (unsigned short*)(ws + 123666432);
  float* meta = h1;

  unsigned long long* pairs = (unsigned long long*)(ws + 0);
  int* rowptr = (int*)(ws + 16000000);
  float* dinv = (float*)(ws + 16500000);
  int* ghist = (int*)(ws + 16800000);
  int* gscan = (int*)(ws + 17000000);
  int* bsum = (int*)(ws + 17200000);
  int* csr_src = (int*)(ws + 17500000);

  // ---- casts ----
  cast_bf16<<<(NUM_ITEMS * FEAT_DIM / 8) / 256, 256, 0, stream>>>(item_feat, Af);
  transpose_cast<<<dim3(H1DIM / 32, FEAT_DIM / 32), dim3(32, 8), 0, stream>>>(
      W1, W1t, FEAT_DIM, H1DIM);
  transpose_cast<<<dim3(HID / 32, H1DIM / 32), dim3(32, 8), 0, stream>>>(
      W2, W2t, H1DIM, HID);

  // ---- item metadata MLP (bf16 MFMA GEMMs) ----
  gemm_mfma_bias<<<dim3(H1DIM / 128, (NUM_ITEMS + 127) / 128), 256, 0, stream>>>(
      Af, W1t, b1, h1, NUM_ITEMS, H1DIM, FEAT_DIM);
  ln_relu_w512_bf16<<<NUM_ITEMS, 256, 0, stream>>>(h1, g1, be1, h1b);
  gemm_mfma_bias<<<dim3(HID / 128, (NUM_ITEMS + 127) / 128), 256, 0, stream>>>(
      h1b, W2t, b2, h2, NUM_ITEMS, HID, H1DIM);
  ln_relu_w128<<<(NUM_ITEMS * 64) / 256, 256, 0, stream>>>(h2, g2, be2,
                                                           NUM_ITEMS);
  gemm3_norm4<<<NUM_ITEMS / 4, 128, 0, stream>>>(h2, W3, b3, meta);

  // ---- e0 and out init (consumes meta; h1/h2 regions free afterwards) ----
  build_e0<<<(NUM_NODES * HID) / 256, 256, 0, stream>>>(emb, meta, mw, xAf, out);

  // ---- atomic-free CSR build ----
  p1_hist<<<NBL, 256, 0, stream>>>(dst, ghist, E, NBL);
  scan_a<<<NBs, 256, 0, stream>>>(ghist, gscan, bsum, nScan);
  scan_b<<<1, 512, 0, stream>>>(bsum, NBs);
  scan_c<<<NBs, 256, 0, stream>>>(gscan, bsum, nScan);
  p1_scatter<<<NBL, 256, 0, stream>>>(src, dst, gscan, pairs, E, NBL);
  p2_build<<<NBKT, 512, 0, stream>>>(pairs, gscan, rowptr, csr_src, E, NBL);
  calc_dinv2<<<(NUM_NODES + 255) / 256, 256, 0, stream>>>(rowptr, dinv,
                                                          NUM_NODES);

  // ---- 3 propagation layers ----
  const int PG = (NUM_NODES / 2 * 64) / 256;  // 8750 blocks
  spmm_prop<0><<<PG, 256, 0, stream>>>(rowptr, csr_src, dinv, xAf, xBb, out, 1);
  spmm_prop<1><<<PG, 256, 0, stream>>>(rowptr, csr_src, dinv, xBb, xCb, out, 1);
  spmm_prop<1><<<PG, 256, 0, stream>>>(rowptr, csr_src, dinv, xCb, nullptr, out,
                                       0);
}